// Round 1
// baseline (152.524 us; speedup 1.0000x reference)
//
#include <hip/hip_runtime.h>
#include <math.h>

// GHM loss, collapsed: loss = LSE(pred)*B - A where
//   A = ratio*sum_{valid & t>p}(t*p) + sum_{valid & t<=p}(t*p)
//   B = ratio*sum_{valid & t>p}(t)   + sum_{valid & t<=p}(t)
//   ratio = (cnt_valid - 0.5*cnt_hist) / max(0.5*cnt_hist, 1)
//   cnt_hist = #valid with g=|sigmoid(p)-t| <= 1.000001 (all bins 0..10)
// Two kernels: streaming partial pass (memory-bound, 134 MB read) + tiny reduce.

#define NT 256
#define MAXNB 2048

__device__ inline void combine_ms(float& m, float& s, float mo, float so) {
    float M = fmaxf(m, mo);
    // fminf guards the (-inf)-(-inf)=NaN case (empty partial): forces scale so 0*1=0
    s = s * exp2f(fminf(m - M, 0.0f)) + so * exp2f(fminf(mo - M, 0.0f));
    m = M;
}

// Full block reduction of (m,s) logsumexp pair + 6 plain sums.
// Result written (by thread 0 only) into out8[0..7].
__device__ inline void block_reduce_write(float m, float s, float* sums, float* out8) {
    #pragma unroll
    for (int off = 32; off > 0; off >>= 1) {
        float mo = __shfl_down(m, off);
        float so = __shfl_down(s, off);
        combine_ms(m, s, mo, so);
        #pragma unroll
        for (int k = 0; k < 6; k++) sums[k] += __shfl_down(sums[k], off);
    }
    __shared__ float red[NT / 64][8];
    int wave = threadIdx.x >> 6;
    int lane = threadIdx.x & 63;
    if (lane == 0) {
        red[wave][0] = m;
        red[wave][1] = s;
        #pragma unroll
        for (int k = 0; k < 6; k++) red[wave][2 + k] = sums[k];
    }
    __syncthreads();
    if (threadIdx.x == 0) {
        float M = red[0][0], S = red[0][1];
        float acc[6];
        #pragma unroll
        for (int k = 0; k < 6; k++) acc[k] = red[0][2 + k];
        #pragma unroll
        for (int w = 1; w < NT / 64; w++) {
            combine_ms(M, S, red[w][0], red[w][1]);
            #pragma unroll
            for (int k = 0; k < 6; k++) acc[k] += red[w][2 + k];
        }
        out8[0] = M;
        out8[1] = S;
        #pragma unroll
        for (int k = 0; k < 6; k++) out8[2 + k] = acc[k];
    }
}

__global__ __launch_bounds__(NT) void ghm_pass1(const float* __restrict__ pred,
                                                const float* __restrict__ targ,
                                                float* __restrict__ ws, int n) {
    const float L2E = 1.4426950408889634f;  // log2(e): work in exp2 domain
    int tid = blockIdx.x * NT + threadIdx.x;
    int nthreads = gridDim.x * NT;
    int n4 = n >> 2;

    float m = -INFINITY, s = 0.0f;
    // sums: 0=cnt_valid 1=cnt_hist 2=A_gt 3=A_le 4=B_gt 5=B_le
    float sums[6] = {0.f, 0.f, 0.f, 0.f, 0.f, 0.f};

    const float4* p4 = (const float4*)pred;
    const float4* t4 = (const float4*)targ;

    for (int i = tid; i < n4; i += nthreads) {
        float4 p = p4[i];
        float4 t = t4[i];
        float pv[4] = {p.x, p.y, p.z, p.w};
        float tv[4] = {t.x, t.y, t.z, t.w};
        float y[4];
        float m4 = -INFINITY;
        #pragma unroll
        for (int j = 0; j < 4; j++) {
            y[j] = pv[j] * L2E;
            m4 = fmaxf(m4, y[j]);
        }
        // online logsumexp merge, amortized over 4 elements
        float M = fmaxf(m, m4);
        s *= exp2f(fminf(m - M, 0.0f));
        #pragma unroll
        for (int j = 0; j < 4; j++) s += exp2f(y[j] - M);
        m = M;

        #pragma unroll
        for (int j = 0; j < 4; j++) {
            float pj = pv[j], tj = tv[j];
            bool vfin = isfinite(tj) && (pj == pj);  // == reference valid mask
            float sig = 1.0f / (1.0f + exp2f(-y[j]));  // exp(-p) = 2^(-y)
            float g = fabsf(sig - tj);
            sums[0] += vfin ? 1.0f : 0.0f;
            sums[1] += (vfin && (g <= 1.000001f)) ? 1.0f : 0.0f;
            float tw = vfin ? tj : 0.0f;
            bool gt = tj > pj;
            float twp = tw * pj;
            sums[2] += gt ? twp : 0.0f;
            sums[3] += gt ? 0.0f : twp;
            sums[4] += gt ? tw : 0.0f;
            sums[5] += gt ? 0.0f : tw;
        }
    }

    // scalar tail (n % 4 != 0), handled by one thread — no-op for n = 16M
    if (tid == 0) {
        for (int i = n4 << 2; i < n; i++) {
            float pj = pred[i], tj = targ[i];
            float yj = pj * L2E;
            float M = fmaxf(m, yj);
            s = s * exp2f(fminf(m - M, 0.0f)) + exp2f(yj - M);
            m = M;
            bool vfin = isfinite(tj) && (pj == pj);
            float sig = 1.0f / (1.0f + exp2f(-yj));
            float g = fabsf(sig - tj);
            sums[0] += vfin ? 1.0f : 0.0f;
            sums[1] += (vfin && (g <= 1.000001f)) ? 1.0f : 0.0f;
            float tw = vfin ? tj : 0.0f;
            bool gt = tj > pj;
            float twp = tw * pj;
            sums[2] += gt ? twp : 0.0f;
            sums[3] += gt ? 0.0f : twp;
            sums[4] += gt ? tw : 0.0f;
            sums[5] += gt ? 0.0f : tw;
        }
    }

    block_reduce_write(m, s, sums, &ws[(size_t)blockIdx.x * 8]);
}

__global__ __launch_bounds__(NT) void ghm_pass2(const float* __restrict__ ws,
                                                float* __restrict__ out, int nb) {
    float m = -INFINITY, s = 0.0f;
    float sums[6] = {0.f, 0.f, 0.f, 0.f, 0.f, 0.f};
    for (int i = threadIdx.x; i < nb; i += NT) {
        const float* p = &ws[(size_t)i * 8];
        combine_ms(m, s, p[0], p[1]);
        #pragma unroll
        for (int k = 0; k < 6; k++) sums[k] += p[2 + k];
    }
    float res[8];
    block_reduce_write(m, s, sums, res);
    if (threadIdx.x == 0) {
        float M = res[0], S = res[1];
        float cnt = res[2], hcnt = res[3];
        float agt = res[4], ale = res[5], bgt = res[6], ble = res[7];
        float tp0 = 0.5f * hcnt;            // sum(acc_sum) = (1-momentum)*counts
        float tneg = cnt - tp0;             // computed pre-clamp (as in reference)
        float tpos = fmaxf(tp0, 1.0f);
        float ratio = tneg / tpos;
        float A = ratio * agt + ale;
        float B = ratio * bgt + ble;
        float lse = (M + log2f(S)) * 0.69314718055994531f;  // back to natural log
        out[0] = lse * B - A;
    }
}

extern "C" void kernel_launch(void* const* d_in, const int* in_sizes, int n_in,
                              void* d_out, int out_size, void* d_ws, size_t ws_size,
                              hipStream_t stream) {
    const float* pred = (const float*)d_in[0];
    const float* targ = (const float*)d_in[1];
    float* out = (float*)d_out;
    float* ws = (float*)d_ws;
    int n = in_sizes[0];

    int nb = MAXNB;
    size_t need = (size_t)nb * 8 * sizeof(float);
    if (ws_size < need) {
        nb = (int)(ws_size / (8 * sizeof(float)));
        if (nb < 1) nb = 1;
    }

    ghm_pass1<<<nb, NT, 0, stream>>>(pred, targ, ws, n);
    ghm_pass2<<<1, NT, 0, stream>>>(ws, out, nb);
}